// Round 7
// baseline (192.213 us; speedup 1.0000x reference)
//
#include <hip/hip_runtime.h>
#include <hip/hip_bf16.h>

#define B_    8
#define N_    1024
#define DIM_  512
#define H_    8
#define DH_   64
#define SCALE_ 0.125f

typedef unsigned short u16;
typedef __attribute__((ext_vector_type(8))) short bf16x8;
typedef __attribute__((ext_vector_type(4))) short bf16x4;
typedef __attribute__((ext_vector_type(4))) float f32x4;

struct SwTrue  { static constexpr bool value = true;  };
struct SwFalse { static constexpr bool value = false; };

__device__ __forceinline__ u16 f2bf(float f) {
  union { float f; unsigned u; } v; v.f = f;
  return (u16)((v.u + 0x7fffu + ((v.u >> 16) & 1u)) >> 16);
}
__device__ __forceinline__ unsigned pack2(float a, float b) {
  return (unsigned)f2bf(a) | ((unsigned)f2bf(b) << 16);
}
__device__ __forceinline__ void cp16(const void* g, void* l) {
  __builtin_amdgcn_global_load_lds(
      (const __attribute__((address_space(1))) unsigned*)g,
      (__attribute__((address_space(3))) unsigned*)l, 16, 0, 0);
}

// ---------------- Kernel 0: fp32 -> bf16 convert (weights only now) --------
__global__ __launch_bounds__(256) void convert_kernel(
    const float* __restrict__ Wq, const float* __restrict__ Wp,
    u16* __restrict__ Wqb, u16* __restrict__ Wpb) {
  const int NQ4 = (3 * DIM_ * DIM_) / 4;       // 196608
  const int NP4 = (DIM_ * DIM_) / 4;           // 65536
  const int total = NQ4 + NP4;                 // 262144
  const int i = blockIdx.x * 256 + threadIdx.x;
  if (i >= total) return;
  const float* s; u16* d; int off;
  if (i < NQ4) { s = Wq; d = Wqb; off = i; }
  else         { s = Wp; d = Wpb; off = i - NQ4; }
  float4 f = *(const float4*)(s + (size_t)off * 4);
  uint2 u; u.x = pack2(f.x, f.y); u.y = pack2(f.z, f.w);
  *(uint2*)(d + (size_t)off * 4) = u;
}

// ---------------- Kernel 1: QKV GEMM 128x64, X fp32 direct, swap-epilogue --
// C[m][j] = sum_k X[m][k] * W[j][k].
// X staged fp32->bf16 in-register (no Xb pass). For Q/K tiles the MFMA
// operands are SWAPPED so the acc reg-index runs along d -> ushort4 stores.
__global__ __launch_bounds__(256, 4) void qkv_gemm(
    const float* __restrict__ X, const u16* __restrict__ Bb,
    u16* __restrict__ Q, u16* __restrict__ K, u16* __restrict__ Vt) {
  __shared__ __align__(16) u16 sA[128 * 64];
  __shared__ __align__(16) u16 sB[64 * 64];
  const int t = threadIdx.x;
  const int wv = t >> 6, lane = t & 63, quad = (lane >> 4) & 3, l15 = lane & 15;
  const int m0 = blockIdx.y * 128;
  const int n0 = blockIdx.x * 64;

  // X staging coords: row xr(+32*ii), chunk xc; LDS chunk xc holds global
  // chunk xc^(row&7) (row&7 == xr&7) to match the fragment-read XOR.
  const int xr = t >> 3, xc = t & 7;
  const float* xsrc = X + (size_t)(m0 + xr) * DIM_ + ((xc ^ (xr & 7)) << 3);
  u16* xdst = &sA[xr * 64 + xc * 8];

  // W staging via global_load_lds (pre-swizzled global source)
  const int srow = lane >> 3;
  const int schunk = (lane & 7) ^ srow;
  const size_t gb = (size_t)(n0 + srow) * DIM_ + schunk * 8;

  const int tsel = n0 >> 9;   // 0=Q,1=K,2=V

  f32x4 zero = {0.f, 0.f, 0.f, 0.f};
  f32x4 acc[2][4];
#pragma unroll
  for (int i = 0; i < 2; i++)
#pragma unroll
    for (int j = 0; j < 4; j++) acc[i][j] = zero;

  float4 xf[4][2];
#pragma unroll
  for (int ii = 0; ii < 4; ii++) {
    const float* p = xsrc + (size_t)ii * 32 * DIM_;
    xf[ii][0] = *(const float4*)p;
    xf[ii][1] = *(const float4*)(p + 4);
  }

  auto kloop = [&](auto swv) {
    constexpr bool SW = decltype(swv)::value;
    for (int k0 = 0; k0 < DIM_; k0 += 64) {
      __syncthreads();
      // X regs -> sA (bf16 packed)
#pragma unroll
      for (int ii = 0; ii < 4; ii++) {
        uint4 u;
        u.x = pack2(xf[ii][0].x, xf[ii][0].y);
        u.y = pack2(xf[ii][0].z, xf[ii][0].w);
        u.z = pack2(xf[ii][1].x, xf[ii][1].y);
        u.w = pack2(xf[ii][1].z, xf[ii][1].w);
        *(uint4*)(xdst + ii * 32 * 64) = u;
      }
      // W tile via async LDS copy
#pragma unroll
      for (int i = 0; i < 2; i++) {
        const int rb = 16 * wv + 8 * i;
        cp16(Bb + gb + (size_t)rb * DIM_ + k0, &sB[rb * 64]);
      }
      // prefetch next X k-slab
      if (k0 < DIM_ - 64) {
#pragma unroll
        for (int ii = 0; ii < 4; ii++) {
          const float* p = xsrc + (size_t)ii * 32 * DIM_ + k0 + 64;
          xf[ii][0] = *(const float4*)p;
          xf[ii][1] = *(const float4*)(p + 4);
        }
      }
      __syncthreads();
#pragma unroll
      for (int ks = 0; ks < 2; ks++) {
        bf16x8 af[2], bfv[4];
#pragma unroll
        for (int i = 0; i < 2; i++)
          af[i] = *(const bf16x8*)&sA[(wv * 32 + 16 * i + l15) * 64 +
                                      (((ks << 2) | quad) ^ (l15 & 7)) * 8];
#pragma unroll
        for (int j = 0; j < 4; j++)
          bfv[j] = *(const bf16x8*)&sB[(16 * j + l15) * 64 +
                                       (((ks << 2) | quad) ^ (l15 & 7)) * 8];
#pragma unroll
        for (int i = 0; i < 2; i++)
#pragma unroll
          for (int j = 0; j < 4; j++) {
            if (SW)
              acc[i][j] = __builtin_amdgcn_mfma_f32_16x16x32_bf16(bfv[j], af[i], acc[i][j], 0, 0, 0);
            else
              acc[i][j] = __builtin_amdgcn_mfma_f32_16x16x32_bf16(af[i], bfv[j], acc[i][j], 0, 0, 0);
          }
      }
    }
  };

  const int h = (n0 >> 6) & 7;     // uniform per block (BN=64)
  if (tsel == 2) {
    kloop(SwFalse{});
    // V: col=l15 -> d, reg -> nb; ushort4 along nb into Vt[bh][d][n]
#pragma unroll
    for (int j = 0; j < 4; j++) {
      const int d = 16 * j + l15;
#pragma unroll
      for (int i = 0; i < 2; i++) {
        const int mbase = m0 + wv * 32 + 16 * i + (quad << 2);
        const int b = mbase >> 10, nb = mbase & 1023;
        const size_t bh = (size_t)(b * H_ + h);
        ushort4 v4;
        v4.x = f2bf(acc[i][j][0]); v4.y = f2bf(acc[i][j][1]);
        v4.z = f2bf(acc[i][j][2]); v4.w = f2bf(acc[i][j][3]);
        *(ushort4*)&Vt[(bh * DH_ + d) * N_ + nb] = v4;
      }
    }
  } else {
    kloop(SwTrue{});
    // Q/K swapped: col=l15 -> m, reg -> d; ushort4 along d into [bh][n][d]
    u16* dst = (tsel == 0) ? Q : K;
#pragma unroll
    for (int j = 0; j < 4; j++) {
      const int d = 16 * j + (quad << 2);
#pragma unroll
      for (int i = 0; i < 2; i++) {
        const int m = m0 + wv * 32 + 16 * i + l15;
        const int b = m >> 10, nb = m & 1023;
        const size_t bh = (size_t)(b * H_ + h);
        ushort4 v4;
        v4.x = f2bf(acc[i][j][0]); v4.y = f2bf(acc[i][j][1]);
        v4.z = f2bf(acc[i][j][2]); v4.w = f2bf(acc[i][j][3]);
        *(ushort4*)&dst[(bh * N_ + nb) * DH_ + d] = v4;
      }
    }
  }
}

// ---------------- Kernel 2: flash attention, 512 thr, QBLK=128 -------------
// R7: 8 waves x 16 q-rows per block, grid 512 = 2 blocks/CU = 4 waves/SIMD.
// Combines R6's occupancy with R5's staging amortization (half of R6's
// staging volume & bank-conflict source; 16 waves share each barrier).
// Keeps: P-in-register PV, XOR swizzle, XCD remap, no-max softmax.
__global__ __launch_bounds__(512, 4) void attn_kernel(
    const u16* __restrict__ Q, const u16* __restrict__ K,
    const u16* __restrict__ Vt, const float* __restrict__ bias,
    u16* __restrict__ AO) {
  __shared__ __align__(16) u16 sK[64 * 64];
  __shared__ __align__(16) u16 sV[64 * 64];
  const int t = threadIdx.x;
  const int wv = t >> 6;           // 0..7 -> q-group
  const int lane = t & 63, quad = (lane >> 4) & 3, l15 = lane & 15;

  const int bid = blockIdx.x;
  const int h = bid & 7;           // XCD = bid % 8
  const int s = bid >> 3;          // 0..63 within XCD
  const int nx = s >> 3;           // 0..7 (128-q tiles), outer
  const int b = s & 7;             // 0..7, inner (bias L2 reuse)
  const int n0 = nx << 7;
  const int bh = b * H_ + h;

  const int qg = n0 + 16 * wv + l15;
  bf16x8 qf0, qf1;
  {
    const u16* qa = Q + (((size_t)bh << 10) + qg) * DH_ + (quad << 3);
    qf0 = *(const bf16x8*)qa; qf1 = *(const bf16x8*)(qa + 32);
  }

  const float* bp = bias + (((size_t)h << 10) + qg) * N_ + (quad << 2);

  // staging: 512 threads, row r=t>>3, chunk c8=t&7; one uint4 each for K,V
  const int r = t >> 3, c8 = t & 7;
  const u16* kbase = K + (((size_t)bh << 10) + r) * DH_ + (c8 << 3);
  const u16* vbase = Vt + (((size_t)bh << 6) + r) * N_ + (c8 << 3);
  const int so = r * 128 + ((c8 ^ (r & 7)) << 4);

  // fragment addressing
  const int rx = (l15 & 7) << 4;
  const int frow = l15 * 128;
  const int vhalf = (quad & 1) << 3;

  f32x4 zero = {0.f, 0.f, 0.f, 0.f};
  f32x4 O[4];
  O[0] = zero; O[1] = zero; O[2] = zero; O[3] = zero;
  float lsum = 0.f;

  uint4 kr = *(const uint4*)kbase;
  uint4 vr = *(const uint4*)vbase;

  for (int kt = 0; kt < 16; kt++) {
    __syncthreads();   // previous tile's LDS reads complete
    *(uint4*)((char*)sK + so) = kr;
    *(uint4*)((char*)sV + so) = vr;
    if (kt < 15) {
      kr = *(const uint4*)(kbase + (size_t)(kt + 1) * 64 * DH_);
      vr = *(const uint4*)(vbase + (kt + 1) * 64);
    }
    float4 b4[4];
#pragma unroll
    for (int cb = 0; cb < 4; cb++)
      b4[cb] = *(const float4*)(bp + (kt << 6) + 16 * cb);
    __syncthreads();   // staging visible

    // ---- QK^T: S^T[key][q] ----
    bf16x8 kf[8];
#pragma unroll
    for (int ks = 0; ks < 2; ks++)
#pragma unroll
      for (int cb = 0; cb < 4; cb++)
        kf[ks * 4 + cb] = *(const bf16x8*)((const char*)sK + cb * 2048 + frow +
                                           (((ks << 6) | (quad << 4)) ^ rx));

    f32x4 S[4];
    S[0] = zero; S[1] = zero; S[2] = zero; S[3] = zero;
    __builtin_amdgcn_s_setprio(1);
#pragma unroll
    for (int ks = 0; ks < 2; ks++) {
      const bf16x8 qf = ks ? qf1 : qf0;
#pragma unroll
      for (int cb = 0; cb < 4; cb++)
        S[cb] = __builtin_amdgcn_mfma_f32_16x16x32_bf16(kf[ks * 4 + cb], qf, S[cb], 0, 0, 0);
    }
    __builtin_amdgcn_s_setprio(0);

    // ---- no-max softmax -> packed bf16 P in registers ----
    bf16x4 p[4];
#pragma unroll
    for (int cb = 0; cb < 4; cb++) {
      float p0 = __expf(fmaf(S[cb][0], SCALE_, b4[cb].x));
      float p1 = __expf(fmaf(S[cb][1], SCALE_, b4[cb].y));
      float p2 = __expf(fmaf(S[cb][2], SCALE_, b4[cb].z));
      float p3 = __expf(fmaf(S[cb][3], SCALE_, b4[cb].w));
      lsum += (p0 + p1) + (p2 + p3);
      uint2 pk; pk.x = pack2(p0, p1); pk.y = pack2(p2, p3);
      p[cb] = __builtin_bit_cast(bf16x4, pk);
    }

    // ---- PV: O^T[d][q] += V^T . P^T, B from registers ----
    __builtin_amdgcn_s_setprio(1);
#pragma unroll
    for (int cbp = 0; cbp < 4; cbp++) {
      bf16x4 vf[4];
#pragma unroll
      for (int cb = 0; cb < 4; cb++) {
        const int ch = ((((2 * cb + (quad >> 1)) << 4)) ^ rx) + vhalf;
        vf[cb] = *(const bf16x4*)((const char*)sV + cbp * 2048 + frow + ch);
      }
#pragma unroll
      for (int cb = 0; cb < 4; cb++)
        O[cbp] = __builtin_amdgcn_mfma_f32_16x16x16bf16_1k(vf[cb], p[cb], O[cbp], 0, 0, 0);
    }
    __builtin_amdgcn_s_setprio(0);
  }

  // deferred cross-quad sum reduce (keys split across quads)
  lsum += __shfl_xor(lsum, 16);
  lsum += __shfl_xor(lsum, 32);
  const float inv = 1.f / lsum;
#pragma unroll
  for (int cb = 0; cb < 4; cb++) {
    ushort4 o4;
    o4.x = f2bf(O[cb][0] * inv); o4.y = f2bf(O[cb][1] * inv);
    o4.z = f2bf(O[cb][2] * inv); o4.w = f2bf(O[cb][3] * inv);
    *(ushort4*)&AO[(((size_t)b << 10) + qg) * DIM_ + h * DH_ + 16 * cb + (quad << 2)] = o4;
  }
}

// ---------------- Kernel 3: output projection 128x64, swap-epilogue --------
// Swapped MFMA: acc reg-index runs along out-col -> 8 float4 stores + vec bias
__global__ __launch_bounds__(256, 4) void proj_gemm(
    const u16* __restrict__ Ab, const u16* __restrict__ Bb,
    const float* __restrict__ Pb, float* __restrict__ Out) {
  __shared__ __align__(16) u16 sA[128 * 64];
  __shared__ __align__(16) u16 sB[64 * 64];
  const int t = threadIdx.x;
  const int wv = t >> 6, lane = t & 63, quad = (lane >> 4) & 3, l15 = lane & 15;
  const int m0 = blockIdx.y * 128;
  const int n0 = blockIdx.x * 64;

  const int srow = lane >> 3;
  const int schunk = (lane & 7) ^ srow;
  const size_t ga = (size_t)(m0 + srow) * DIM_ + schunk * 8;
  const size_t gb = (size_t)(n0 + srow) * DIM_ + schunk * 8;

  f32x4 zero = {0.f, 0.f, 0.f, 0.f};
  f32x4 acc[2][4];
#pragma unroll
  for (int i = 0; i < 2; i++)
#pragma unroll
    for (int j = 0; j < 4; j++) acc[i][j] = zero;

  for (int k0 = 0; k0 < DIM_; k0 += 64) {
    __syncthreads();
#pragma unroll
    for (int i = 0; i < 4; i++) {
      const int rb = 32 * wv + 8 * i;
      cp16(Ab + ga + (size_t)rb * DIM_ + k0, &sA[rb * 64]);
    }
#pragma unroll
    for (int i = 0; i < 2; i++) {
      const int rb = 16 * wv + 8 * i;
      cp16(Bb + gb + (size_t)rb * DIM_ + k0, &sB[rb * 64]);
    }
    __syncthreads();
#pragma unroll
    for (int ks = 0; ks < 2; ks++) {
      bf16x8 af[2], bfv[4];
#pragma unroll
      for (int i = 0; i < 2; i++)
        af[i] = *(const bf16x8*)&sA[(wv * 32 + 16 * i + l15) * 64 +
                                    (((ks << 2) | quad) ^ (l15 & 7)) * 8];
#pragma unroll
      for (int j = 0; j < 4; j++)
        bfv[j] = *(const bf16x8*)&sB[(16 * j + l15) * 64 +
                                     (((ks << 2) | quad) ^ (l15 & 7)) * 8];
#pragma unroll
      for (int i = 0; i < 2; i++)
#pragma unroll
        for (int j = 0; j < 4; j++)
          acc[i][j] = __builtin_amdgcn_mfma_f32_16x16x32_bf16(bfv[j], af[i], acc[i][j], 0, 0, 0);
    }
  }

#pragma unroll
  for (int j = 0; j < 4; j++) {
    const int col = n0 + 16 * j + (quad << 2);
    const float4 pb4 = *(const float4*)&Pb[col];
#pragma unroll
    for (int i = 0; i < 2; i++) {
      const int m = m0 + wv * 32 + 16 * i + l15;
      float4 o;
      o.x = acc[i][j][0] + pb4.x; o.y = acc[i][j][1] + pb4.y;
      o.z = acc[i][j][2] + pb4.z; o.w = acc[i][j][3] + pb4.w;
      *(float4*)&Out[(size_t)m * DIM_ + col] = o;
    }
  }
}

extern "C" void kernel_launch(void* const* d_in, const int* in_sizes, int n_in,
                              void* d_out, int out_size, void* d_ws, size_t ws_size,
                              hipStream_t stream) {
  const float* x      = (const float*)d_in[0];
  const float* rpe    = (const float*)d_in[1];
  const float* qkv_w  = (const float*)d_in[2];
  const float* proj_w = (const float*)d_in[3];
  const float* proj_b = (const float*)d_in[4];
  float* out = (float*)d_out;

  const size_t perbuf = (size_t)B_ * N_ * DIM_;   // 4,194,304
  u16* AO  = (u16*)d_ws;
  u16* Q   = AO + perbuf;
  u16* K   = Q + perbuf;
  u16* Vt  = K + perbuf;
  u16* Wqb = Vt + perbuf;                     // 786,432
  u16* Wpb = Wqb + (size_t)3 * DIM_ * DIM_;   // 262,144

  convert_kernel<<<1024, 256, 0, stream>>>(qkv_w, proj_w, Wqb, Wpb);
  qkv_gemm<<<dim3(24, 64), 256, 0, stream>>>(x, Wqb, Q, K, Vt);
  attn_kernel<<<512, 512, 0, stream>>>(Q, K, Vt, rpe, AO);
  proj_gemm<<<dim3(8, 64), 256, 0, stream>>>(AO, Wpb, proj_b, out);
}

// Round 8
// 166.965 us; speedup vs baseline: 1.1512x; 1.1512x over previous
//
#include <hip/hip_runtime.h>
#include <hip/hip_bf16.h>

#define B_    8
#define N_    1024
#define DIM_  512
#define H_    8
#define DH_   64
#define SCALE_ 0.125f

typedef unsigned short u16;
typedef __attribute__((ext_vector_type(8))) short bf16x8;
typedef __attribute__((ext_vector_type(4))) short bf16x4;
typedef __attribute__((ext_vector_type(4))) float f32x4;

__device__ __forceinline__ u16 f2bf(float f) {
  union { float f; unsigned u; } v; v.f = f;
  return (u16)((v.u + 0x7fffu + ((v.u >> 16) & 1u)) >> 16);
}
__device__ __forceinline__ unsigned pack2(float a, float b) {
  return (unsigned)f2bf(a) | ((unsigned)f2bf(b) << 16);
}
__device__ __forceinline__ void cp16(const void* g, void* l) {
  __builtin_amdgcn_global_load_lds(
      (const __attribute__((address_space(1))) unsigned*)g,
      (__attribute__((address_space(3))) unsigned*)l, 16, 0, 0);
}

// ---------------- Kernel 0: fp32 -> bf16 convert (X, qkv_w, proj_w) --------
__global__ __launch_bounds__(256) void convert_kernel(
    const float* __restrict__ X, const float* __restrict__ Wq,
    const float* __restrict__ Wp, u16* __restrict__ Xb,
    u16* __restrict__ Wqb, u16* __restrict__ Wpb) {
  const int NX4 = (B_ * N_ * DIM_) / 4;        // 1048576
  const int NQ4 = (3 * DIM_ * DIM_) / 4;       // 196608
  const int NP4 = (DIM_ * DIM_) / 4;           // 65536
  const int total = NX4 + NQ4 + NP4;
  const int stride = gridDim.x * 256;
  for (int i = blockIdx.x * 256 + threadIdx.x; i < total; i += stride) {
    const float* s; u16* d; int off;
    if (i < NX4)            { s = X;  d = Xb;  off = i; }
    else if (i < NX4 + NQ4) { s = Wq; d = Wqb; off = i - NX4; }
    else                    { s = Wp; d = Wpb; off = i - NX4 - NQ4; }
    float4 f = *(const float4*)(s + (size_t)off * 4);
    uint2 u; u.x = pack2(f.x, f.y); u.y = pack2(f.z, f.w);
    *(uint2*)(d + (size_t)off * 4) = u;
  }
}

// ---------------- Kernel 1: QKV GEMM 128x64, dbuf + counted vmcnt ----------
// T4 schedule: stage tile t+1 into the other LDS buffer, wait ONLY for tile
// t's 6 loads (s_waitcnt vmcnt(6)), raw barriers -- next tile's loads stay in
// flight across the whole compute phase. Epilogue = R6 orientation (lanes
// cover contiguous columns; R7's per-lane vectors scattered across rows were
// a 1.8x write amplification, WRITE_SIZE 42.7 vs 24 MB).
__global__ __launch_bounds__(256, 3) void qkv_gemm(
    const u16* __restrict__ Ab, const u16* __restrict__ Bb,
    u16* __restrict__ Q, u16* __restrict__ K, u16* __restrict__ Vt) {
  __shared__ __align__(16) u16 sA[2][128 * 64];
  __shared__ __align__(16) u16 sB[2][64 * 64];
  const int t = threadIdx.x;
  const int wv = t >> 6, lane = t & 63, quad = (lane >> 4) & 3, l15 = lane & 15;
  const int m0 = blockIdx.y * 128;
  const int n0 = blockIdx.x * 64;

  const int srow = lane >> 3;                 // 0..7
  const int schunk = (lane & 7) ^ srow;       // xor-swizzled source chunk
  const size_t ga = (size_t)(m0 + srow) * DIM_ + schunk * 8;
  const size_t gb = (size_t)(n0 + srow) * DIM_ + schunk * 8;

  f32x4 zero = {0.f, 0.f, 0.f, 0.f};
  f32x4 acc[2][4];
#pragma unroll
  for (int i = 0; i < 2; i++)
#pragma unroll
    for (int j = 0; j < 4; j++) acc[i][j] = zero;

  auto stage = [&](int buf, int k0) {
#pragma unroll
    for (int i = 0; i < 4; i++) {
      const int rb = 32 * wv + 8 * i;
      cp16(Ab + ga + (size_t)rb * DIM_ + k0, &sA[buf][rb * 64]);
    }
#pragma unroll
    for (int i = 0; i < 2; i++) {
      const int rb = 16 * wv + 8 * i;
      cp16(Bb + gb + (size_t)rb * DIM_ + k0, &sB[buf][rb * 64]);
    }
  };

  stage(0, 0);                       // 6 loads in flight
  for (int kt = 0; kt < 8; kt++) {
    const int cur = kt & 1;
    asm volatile("s_barrier" ::: "memory");        // prev iter's reads done
    if (kt < 7) {
      stage(cur ^ 1, (kt + 1) * 64);               // +6 loads (tile kt+1)
      asm volatile("s_waitcnt vmcnt(6)" ::: "memory");  // tile kt landed (mine)
    } else {
      asm volatile("s_waitcnt vmcnt(0)" ::: "memory");
    }
    asm volatile("s_barrier" ::: "memory");        // everyone's share landed
#pragma unroll
    for (int ks = 0; ks < 2; ks++) {
      bf16x8 af[2], bfv[4];
#pragma unroll
      for (int i = 0; i < 2; i++)
        af[i] = *(const bf16x8*)&sA[cur][(wv * 32 + 16 * i + l15) * 64 +
                                        (((ks << 2) | quad) ^ (l15 & 7)) * 8];
#pragma unroll
      for (int j = 0; j < 4; j++)
        bfv[j] = *(const bf16x8*)&sB[cur][(16 * j + l15) * 64 +
                                         (((ks << 2) | quad) ^ (l15 & 7)) * 8];
      __builtin_amdgcn_s_setprio(1);
#pragma unroll
      for (int i = 0; i < 2; i++)
#pragma unroll
        for (int j = 0; j < 4; j++)
          acc[i][j] = __builtin_amdgcn_mfma_f32_16x16x32_bf16(af[i], bfv[j], acc[i][j], 0, 0, 0);
      __builtin_amdgcn_s_setprio(0);
    }
  }

  const int tsel = n0 >> 9;   // 0=Q,1=K,2=V (512-col boundaries)
  const int h = (n0 >> 6) & 7;
#pragma unroll
  for (int j = 0; j < 4; j++) {
    const int jg = n0 + 16 * j + l15;
    const int d = jg & 63;
#pragma unroll
    for (int i = 0; i < 2; i++) {
      const int mbase = m0 + wv * 32 + 16 * i + quad * 4;
      const int b = mbase >> 10, nb = mbase & 1023;
      const size_t bh = (size_t)(b * H_ + h);
      if (tsel == 2) {
        ushort4 v4;
        v4.x = f2bf(acc[i][j][0]); v4.y = f2bf(acc[i][j][1]);
        v4.z = f2bf(acc[i][j][2]); v4.w = f2bf(acc[i][j][3]);
        *(ushort4*)&Vt[(bh * DH_ + d) * N_ + nb] = v4;
      } else {
        u16* dst = (tsel == 0 ? Q : K);
#pragma unroll
        for (int rr = 0; rr < 4; rr++)
          dst[(bh * N_ + nb + rr) * DH_ + d] = f2bf(acc[i][j][rr]);
      }
    }
  }
}

// ---------------- Kernel 2: flash attention, 512 thr, QBLK=128 (R7) --------
__global__ __launch_bounds__(512, 4) void attn_kernel(
    const u16* __restrict__ Q, const u16* __restrict__ K,
    const u16* __restrict__ Vt, const float* __restrict__ bias,
    u16* __restrict__ AO) {
  __shared__ __align__(16) u16 sK[64 * 64];
  __shared__ __align__(16) u16 sV[64 * 64];
  const int t = threadIdx.x;
  const int wv = t >> 6;           // 0..7 -> q-group
  const int lane = t & 63, quad = (lane >> 4) & 3, l15 = lane & 15;

  const int bid = blockIdx.x;
  const int h = bid & 7;           // XCD = bid % 8
  const int s = bid >> 3;          // 0..63 within XCD
  const int nx = s >> 3;           // 0..7 (128-q tiles), outer
  const int b = s & 7;             // 0..7, inner (bias L2 reuse)
  const int n0 = nx << 7;
  const int bh = b * H_ + h;

  const int qg = n0 + 16 * wv + l15;
  bf16x8 qf0, qf1;
  {
    const u16* qa = Q + (((size_t)bh << 10) + qg) * DH_ + (quad << 3);
    qf0 = *(const bf16x8*)qa; qf1 = *(const bf16x8*)(qa + 32);
  }

  const float* bp = bias + (((size_t)h << 10) + qg) * N_ + (quad << 2);

  // staging: 512 threads, row r=t>>3, chunk c8=t&7; one uint4 each for K,V
  const int r = t >> 3, c8 = t & 7;
  const u16* kbase = K + (((size_t)bh << 10) + r) * DH_ + (c8 << 3);
  const u16* vbase = Vt + (((size_t)bh << 6) + r) * N_ + (c8 << 3);
  const int so = r * 128 + ((c8 ^ (r & 7)) << 4);

  // fragment addressing
  const int rx = (l15 & 7) << 4;
  const int frow = l15 * 128;
  const int vhalf = (quad & 1) << 3;

  f32x4 zero = {0.f, 0.f, 0.f, 0.f};
  f32x4 O[4];
  O[0] = zero; O[1] = zero; O[2] = zero; O[3] = zero;
  float lsum = 0.f;

  uint4 kr = *(const uint4*)kbase;
  uint4 vr = *(const uint4*)vbase;

  for (int kt = 0; kt < 16; kt++) {
    __syncthreads();   // previous tile's LDS reads complete
    *(uint4*)((char*)sK + so) = kr;
    *(uint4*)((char*)sV + so) = vr;
    if (kt < 15) {
      kr = *(const uint4*)(kbase + (size_t)(kt + 1) * 64 * DH_);
      vr = *(const uint4*)(vbase + (kt + 1) * 64);
    }
    float4 b4[4];
#pragma unroll
    for (int cb = 0; cb < 4; cb++)
      b4[cb] = *(const float4*)(bp + (kt << 6) + 16 * cb);
    __syncthreads();   // staging visible

    // ---- QK^T: S^T[key][q] ----
    bf16x8 kf[8];
#pragma unroll
    for (int ks = 0; ks < 2; ks++)
#pragma unroll
      for (int cb = 0; cb < 4; cb++)
        kf[ks * 4 + cb] = *(const bf16x8*)((const char*)sK + cb * 2048 + frow +
                                           (((ks << 6) | (quad << 4)) ^ rx));

    f32x4 S[4];
    S[0] = zero; S[1] = zero; S[2] = zero; S[3] = zero;
    __builtin_amdgcn_s_setprio(1);
#pragma unroll
    for (int ks = 0; ks < 2; ks++) {
      const bf16x8 qf = ks ? qf1 : qf0;
#pragma unroll
      for (int cb = 0; cb < 4; cb++)
        S[cb] = __builtin_amdgcn_mfma_f32_16x16x32_bf16(kf[ks * 4 + cb], qf, S[cb], 0, 0, 0);
    }
    __builtin_amdgcn_s_setprio(0);

    // ---- no-max softmax -> packed bf16 P in registers ----
    bf16x4 p[4];
#pragma unroll
    for (int cb = 0; cb < 4; cb++) {
      float p0 = __expf(fmaf(S[cb][0], SCALE_, b4[cb].x));
      float p1 = __expf(fmaf(S[cb][1], SCALE_, b4[cb].y));
      float p2 = __expf(fmaf(S[cb][2], SCALE_, b4[cb].z));
      float p3 = __expf(fmaf(S[cb][3], SCALE_, b4[cb].w));
      lsum += (p0 + p1) + (p2 + p3);
      uint2 pk; pk.x = pack2(p0, p1); pk.y = pack2(p2, p3);
      p[cb] = __builtin_bit_cast(bf16x4, pk);
    }

    // ---- PV: O^T[d][q] += V^T . P^T, B from registers ----
    __builtin_amdgcn_s_setprio(1);
#pragma unroll
    for (int cbp = 0; cbp < 4; cbp++) {
      bf16x4 vf[4];
#pragma unroll
      for (int cb = 0; cb < 4; cb++) {
        const int ch = ((((2 * cb + (quad >> 1)) << 4)) ^ rx) + vhalf;
        vf[cb] = *(const bf16x4*)((const char*)sV + cbp * 2048 + frow + ch);
      }
#pragma unroll
      for (int cb = 0; cb < 4; cb++)
        O[cbp] = __builtin_amdgcn_mfma_f32_16x16x16bf16_1k(vf[cb], p[cb], O[cbp], 0, 0, 0);
    }
    __builtin_amdgcn_s_setprio(0);
  }

  // deferred cross-quad sum reduce (keys split across quads)
  lsum += __shfl_xor(lsum, 16);
  lsum += __shfl_xor(lsum, 32);
  const float inv = 1.f / lsum;
#pragma unroll
  for (int cb = 0; cb < 4; cb++) {
    ushort4 o4;
    o4.x = f2bf(O[cb][0] * inv); o4.y = f2bf(O[cb][1] * inv);
    o4.z = f2bf(O[cb][2] * inv); o4.w = f2bf(O[cb][3] * inv);
    *(ushort4*)&AO[(((size_t)b << 10) + qg) * DIM_ + h * DH_ + 16 * cb + (quad << 2)] = o4;
  }
}

// ---------------- Kernel 3: output projection 128x64, dbuf + counted vmcnt -
// Same T4 schedule as qkv. Epilogue = R6 orientation (16 lanes cover 64B
// contiguous per quad).
__global__ __launch_bounds__(256, 3) void proj_gemm(
    const u16* __restrict__ Ab, const u16* __restrict__ Bb,
    const float* __restrict__ Pb, float* __restrict__ Out) {
  __shared__ __align__(16) u16 sA[2][128 * 64];
  __shared__ __align__(16) u16 sB[2][64 * 64];
  const int t = threadIdx.x;
  const int wv = t >> 6, lane = t & 63, quad = (lane >> 4) & 3, l15 = lane & 15;
  const int m0 = blockIdx.y * 128;
  const int n0 = blockIdx.x * 64;

  const int srow = lane >> 3;
  const int schunk = (lane & 7) ^ srow;
  const size_t ga = (size_t)(m0 + srow) * DIM_ + schunk * 8;
  const size_t gb = (size_t)(n0 + srow) * DIM_ + schunk * 8;

  f32x4 zero = {0.f, 0.f, 0.f, 0.f};
  f32x4 acc[2][4];
#pragma unroll
  for (int i = 0; i < 2; i++)
#pragma unroll
    for (int j = 0; j < 4; j++) acc[i][j] = zero;

  auto stage = [&](int buf, int k0) {
#pragma unroll
    for (int i = 0; i < 4; i++) {
      const int rb = 32 * wv + 8 * i;
      cp16(Ab + ga + (size_t)rb * DIM_ + k0, &sA[buf][rb * 64]);
    }
#pragma unroll
    for (int i = 0; i < 2; i++) {
      const int rb = 16 * wv + 8 * i;
      cp16(Bb + gb + (size_t)rb * DIM_ + k0, &sB[buf][rb * 64]);
    }
  };

  stage(0, 0);
  for (int kt = 0; kt < 8; kt++) {
    const int cur = kt & 1;
    asm volatile("s_barrier" ::: "memory");
    if (kt < 7) {
      stage(cur ^ 1, (kt + 1) * 64);
      asm volatile("s_waitcnt vmcnt(6)" ::: "memory");
    } else {
      asm volatile("s_waitcnt vmcnt(0)" ::: "memory");
    }
    asm volatile("s_barrier" ::: "memory");
#pragma unroll
    for (int ks = 0; ks < 2; ks++) {
      bf16x8 af[2], bfv[4];
#pragma unroll
      for (int i = 0; i < 2; i++)
        af[i] = *(const bf16x8*)&sA[cur][(wv * 32 + 16 * i + l15) * 64 +
                                        (((ks << 2) | quad) ^ (l15 & 7)) * 8];
#pragma unroll
      for (int j = 0; j < 4; j++)
        bfv[j] = *(const bf16x8*)&sB[cur][(16 * j + l15) * 64 +
                                         (((ks << 2) | quad) ^ (l15 & 7)) * 8];
      __builtin_amdgcn_s_setprio(1);
#pragma unroll
      for (int i = 0; i < 2; i++)
#pragma unroll
        for (int j = 0; j < 4; j++)
          acc[i][j] = __builtin_amdgcn_mfma_f32_16x16x32_bf16(af[i], bfv[j], acc[i][j], 0, 0, 0);
      __builtin_amdgcn_s_setprio(0);
    }
  }

#pragma unroll
  for (int j = 0; j < 4; j++) {
    const int jg = n0 + 16 * j + l15;
    const float pb = Pb[jg];
#pragma unroll
    for (int i = 0; i < 2; i++) {
      const int mbase = m0 + wv * 32 + 16 * i + quad * 4;
#pragma unroll
      for (int rr = 0; rr < 4; rr++)
        Out[(size_t)(mbase + rr) * DIM_ + jg] = acc[i][j][rr] + pb;
    }
  }
}

extern "C" void kernel_launch(void* const* d_in, const int* in_sizes, int n_in,
                              void* d_out, int out_size, void* d_ws, size_t ws_size,
                              hipStream_t stream) {
  const float* x      = (const float*)d_in[0];
  const float* rpe    = (const float*)d_in[1];
  const float* qkv_w  = (const float*)d_in[2];
  const float* proj_w = (const float*)d_in[3];
  const float* proj_b = (const float*)d_in[4];
  float* out = (float*)d_out;

  const size_t perbuf = (size_t)B_ * N_ * DIM_;   // 4,194,304
  u16* Xb  = (u16*)d_ws;          // aliased with AO (lifetimes disjoint)
  u16* Q   = Xb + perbuf;
  u16* K   = Q + perbuf;
  u16* Vt  = K + perbuf;
  u16* Wqb = Vt + perbuf;         // 786,432
  u16* Wpb = Wqb + (size_t)3 * DIM_ * DIM_;  // 262,144
  u16* AO  = Xb;

  convert_kernel<<<2560, 256, 0, stream>>>(x, qkv_w, proj_w, Xb, Wqb, Wpb);
  qkv_gemm<<<dim3(24, 64), 256, 0, stream>>>(Xb, Wqb, Q, K, Vt);
  attn_kernel<<<512, 512, 0, stream>>>(Q, K, Vt, rpe, AO);
  proj_gemm<<<dim3(8, 64), 256, 0, stream>>>(AO, Wpb, proj_b, out);
}

// Round 9
// 162.746 us; speedup vs baseline: 1.1811x; 1.0259x over previous
//
#include <hip/hip_runtime.h>
#include <hip/hip_bf16.h>

#define B_    8
#define N_    1024
#define DIM_  512
#define H_    8
#define DH_   64
#define SCALE_ 0.125f

typedef unsigned short u16;
typedef __attribute__((ext_vector_type(8))) short bf16x8;
typedef __attribute__((ext_vector_type(4))) short bf16x4;
typedef __attribute__((ext_vector_type(4))) float f32x4;

__device__ __forceinline__ u16 f2bf(float f) {
  union { float f; unsigned u; } v; v.f = f;
  return (u16)((v.u + 0x7fffu + ((v.u >> 16) & 1u)) >> 16);
}
__device__ __forceinline__ unsigned pack2(float a, float b) {
  return (unsigned)f2bf(a) | ((unsigned)f2bf(b) << 16);
}
__device__ __forceinline__ void cp16(const void* g, void* l) {
  __builtin_amdgcn_global_load_lds(
      (const __attribute__((address_space(1))) unsigned*)g,
      (__attribute__((address_space(3))) unsigned*)l, 16, 0, 0);
}

// ---------------- Kernel 0: fp32 -> bf16 convert (X, qkv_w, proj_w) --------
__global__ __launch_bounds__(256) void convert_kernel(
    const float* __restrict__ X, const float* __restrict__ Wq,
    const float* __restrict__ Wp, u16* __restrict__ Xb,
    u16* __restrict__ Wqb, u16* __restrict__ Wpb) {
  const int NX4 = (B_ * N_ * DIM_) / 4;        // 1048576
  const int NQ4 = (3 * DIM_ * DIM_) / 4;       // 196608
  const int NP4 = (DIM_ * DIM_) / 4;           // 65536
  const int total = NX4 + NQ4 + NP4;
  const int stride = gridDim.x * 256;
  for (int i = blockIdx.x * 256 + threadIdx.x; i < total; i += stride) {
    const float* s; u16* d; int off;
    if (i < NX4)            { s = X;  d = Xb;  off = i; }
    else if (i < NX4 + NQ4) { s = Wq; d = Wqb; off = i - NX4; }
    else                    { s = Wp; d = Wpb; off = i - NX4 - NQ4; }
    float4 f = *(const float4*)(s + (size_t)off * 4);
    uint2 u; u.x = pack2(f.x, f.y); u.y = pack2(f.z, f.w);
    *(uint2*)(d + (size_t)off * 4) = u;
  }
}

// ---------------- Kernel 1: QKV GEMM 128x64, dbuf + vmcnt + XCD remap ------
// T1: each XCD owns a contiguous 8-panel m-chunk (1 MB of A, L2-resident for
// the whole kernel); n iterates inner so the 8 blocks sharing each 64 KB
// B-panel run temporally adjacent on one XCD. R7 counters: old (24,64) grid
// fetched 76.8 MB (A re-fetched by all 8 XCDs); ideal unique input ~10 MB.
// T4 schedule: stage tile t+1 into the other LDS buffer, s_waitcnt vmcnt(6)
// (wait only tile t's 6 loads), raw barriers.
__global__ __launch_bounds__(256, 3) void qkv_gemm(
    const u16* __restrict__ Ab, const u16* __restrict__ Bb,
    u16* __restrict__ Q, u16* __restrict__ K, u16* __restrict__ Vt) {
  __shared__ __align__(16) u16 sA[2][128 * 64];
  __shared__ __align__(16) u16 sB[2][64 * 64];
  const int t = threadIdx.x;
  const int wv = t >> 6, lane = t & 63, quad = (lane >> 4) & 3, l15 = lane & 15;

  // XCD-aware remap: xcd = bid%8 (round-robin dispatch). m = xcd*8 + s%8,
  // n = s/8 (n-inner => B-panel sharers temporally adjacent on one XCD).
  const int bid = blockIdx.x;
  const int xcd = bid & 7;
  const int s = bid >> 3;            // 0..191, ascending in time per XCD
  const int nti = s >> 3;            // 0..23
  const int m0 = (xcd * 8 + (s & 7)) * 128;
  const int n0 = nti * 64;

  const int srow = lane >> 3;                 // 0..7
  const int schunk = (lane & 7) ^ srow;       // xor-swizzled source chunk
  const size_t ga = (size_t)(m0 + srow) * DIM_ + schunk * 8;
  const size_t gb = (size_t)(n0 + srow) * DIM_ + schunk * 8;

  f32x4 zero = {0.f, 0.f, 0.f, 0.f};
  f32x4 acc[2][4];
#pragma unroll
  for (int i = 0; i < 2; i++)
#pragma unroll
    for (int j = 0; j < 4; j++) acc[i][j] = zero;

  auto stage = [&](int buf, int k0) {
#pragma unroll
    for (int i = 0; i < 4; i++) {
      const int rb = 32 * wv + 8 * i;
      cp16(Ab + ga + (size_t)rb * DIM_ + k0, &sA[buf][rb * 64]);
    }
#pragma unroll
    for (int i = 0; i < 2; i++) {
      const int rb = 16 * wv + 8 * i;
      cp16(Bb + gb + (size_t)rb * DIM_ + k0, &sB[buf][rb * 64]);
    }
  };

  stage(0, 0);                       // 6 loads in flight
  for (int kt = 0; kt < 8; kt++) {
    const int cur = kt & 1;
    asm volatile("s_barrier" ::: "memory");        // prev iter's reads done
    if (kt < 7) {
      stage(cur ^ 1, (kt + 1) * 64);               // +6 loads (tile kt+1)
      asm volatile("s_waitcnt vmcnt(6)" ::: "memory");  // tile kt landed (mine)
    } else {
      asm volatile("s_waitcnt vmcnt(0)" ::: "memory");
    }
    asm volatile("s_barrier" ::: "memory");        // everyone's share landed
#pragma unroll
    for (int ks = 0; ks < 2; ks++) {
      bf16x8 af[2], bfv[4];
#pragma unroll
      for (int i = 0; i < 2; i++)
        af[i] = *(const bf16x8*)&sA[cur][(wv * 32 + 16 * i + l15) * 64 +
                                        (((ks << 2) | quad) ^ (l15 & 7)) * 8];
#pragma unroll
      for (int j = 0; j < 4; j++)
        bfv[j] = *(const bf16x8*)&sB[cur][(16 * j + l15) * 64 +
                                         (((ks << 2) | quad) ^ (l15 & 7)) * 8];
      __builtin_amdgcn_s_setprio(1);
#pragma unroll
      for (int i = 0; i < 2; i++)
#pragma unroll
        for (int j = 0; j < 4; j++)
          acc[i][j] = __builtin_amdgcn_mfma_f32_16x16x32_bf16(af[i], bfv[j], acc[i][j], 0, 0, 0);
      __builtin_amdgcn_s_setprio(0);
    }
  }

  const int tsel = n0 >> 9;   // 0=Q,1=K,2=V (512-col boundaries)
  const int h = (n0 >> 6) & 7;
#pragma unroll
  for (int j = 0; j < 4; j++) {
    const int jg = n0 + 16 * j + l15;
    const int d = jg & 63;
#pragma unroll
    for (int i = 0; i < 2; i++) {
      const int mbase = m0 + wv * 32 + 16 * i + quad * 4;
      const int b = mbase >> 10, nb = mbase & 1023;
      const size_t bh = (size_t)(b * H_ + h);
      if (tsel == 2) {
        ushort4 v4;
        v4.x = f2bf(acc[i][j][0]); v4.y = f2bf(acc[i][j][1]);
        v4.z = f2bf(acc[i][j][2]); v4.w = f2bf(acc[i][j][3]);
        *(ushort4*)&Vt[(bh * DH_ + d) * N_ + nb] = v4;
      } else {
        u16* dst = (tsel == 0 ? Q : K);
#pragma unroll
        for (int rr = 0; rr < 4; rr++)
          dst[(bh * N_ + nb + rr) * DH_ + d] = f2bf(acc[i][j][rr]);
      }
    }
  }
}

// ---------------- Kernel 2: flash attention, 512 thr, QBLK=128 (R8) --------
__global__ __launch_bounds__(512, 4) void attn_kernel(
    const u16* __restrict__ Q, const u16* __restrict__ K,
    const u16* __restrict__ Vt, const float* __restrict__ bias,
    u16* __restrict__ AO) {
  __shared__ __align__(16) u16 sK[64 * 64];
  __shared__ __align__(16) u16 sV[64 * 64];
  const int t = threadIdx.x;
  const int wv = t >> 6;           // 0..7 -> q-group
  const int lane = t & 63, quad = (lane >> 4) & 3, l15 = lane & 15;

  const int bid = blockIdx.x;
  const int h = bid & 7;           // XCD = bid % 8
  const int s = bid >> 3;          // 0..63 within XCD
  const int nx = s >> 3;           // 0..7 (128-q tiles), outer
  const int b = s & 7;             // 0..7, inner (bias L2 reuse)
  const int n0 = nx << 7;
  const int bh = b * H_ + h;

  const int qg = n0 + 16 * wv + l15;
  bf16x8 qf0, qf1;
  {
    const u16* qa = Q + (((size_t)bh << 10) + qg) * DH_ + (quad << 3);
    qf0 = *(const bf16x8*)qa; qf1 = *(const bf16x8*)(qa + 32);
  }

  const float* bp = bias + (((size_t)h << 10) + qg) * N_ + (quad << 2);

  // staging: 512 threads, row r=t>>3, chunk c8=t&7; one uint4 each for K,V
  const int r = t >> 3, c8 = t & 7;
  const u16* kbase = K + (((size_t)bh << 10) + r) * DH_ + (c8 << 3);
  const u16* vbase = Vt + (((size_t)bh << 6) + r) * N_ + (c8 << 3);
  const int so = r * 128 + ((c8 ^ (r & 7)) << 4);

  // fragment addressing
  const int rx = (l15 & 7) << 4;
  const int frow = l15 * 128;
  const int vhalf = (quad & 1) << 3;

  f32x4 zero = {0.f, 0.f, 0.f, 0.f};
  f32x4 O[4];
  O[0] = zero; O[1] = zero; O[2] = zero; O[3] = zero;
  float lsum = 0.f;

  uint4 kr = *(const uint4*)kbase;
  uint4 vr = *(const uint4*)vbase;

  for (int kt = 0; kt < 16; kt++) {
    __syncthreads();   // previous tile's LDS reads complete
    *(uint4*)((char*)sK + so) = kr;
    *(uint4*)((char*)sV + so) = vr;
    if (kt < 15) {
      kr = *(const uint4*)(kbase + (size_t)(kt + 1) * 64 * DH_);
      vr = *(const uint4*)(vbase + (kt + 1) * 64);
    }
    float4 b4[4];
#pragma unroll
    for (int cb = 0; cb < 4; cb++)
      b4[cb] = *(const float4*)(bp + (kt << 6) + 16 * cb);
    __syncthreads();   // staging visible

    // ---- QK^T: S^T[key][q] ----
    bf16x8 kf[8];
#pragma unroll
    for (int ks = 0; ks < 2; ks++)
#pragma unroll
      for (int cb = 0; cb < 4; cb++)
        kf[ks * 4 + cb] = *(const bf16x8*)((const char*)sK + cb * 2048 + frow +
                                           (((ks << 6) | (quad << 4)) ^ rx));

    f32x4 S[4];
    S[0] = zero; S[1] = zero; S[2] = zero; S[3] = zero;
    __builtin_amdgcn_s_setprio(1);
#pragma unroll
    for (int ks = 0; ks < 2; ks++) {
      const bf16x8 qf = ks ? qf1 : qf0;
#pragma unroll
      for (int cb = 0; cb < 4; cb++)
        S[cb] = __builtin_amdgcn_mfma_f32_16x16x32_bf16(kf[ks * 4 + cb], qf, S[cb], 0, 0, 0);
    }
    __builtin_amdgcn_s_setprio(0);

    // ---- no-max softmax -> packed bf16 P in registers ----
    bf16x4 p[4];
#pragma unroll
    for (int cb = 0; cb < 4; cb++) {
      float p0 = __expf(fmaf(S[cb][0], SCALE_, b4[cb].x));
      float p1 = __expf(fmaf(S[cb][1], SCALE_, b4[cb].y));
      float p2 = __expf(fmaf(S[cb][2], SCALE_, b4[cb].z));
      float p3 = __expf(fmaf(S[cb][3], SCALE_, b4[cb].w));
      lsum += (p0 + p1) + (p2 + p3);
      uint2 pk; pk.x = pack2(p0, p1); pk.y = pack2(p2, p3);
      p[cb] = __builtin_bit_cast(bf16x4, pk);
    }

    // ---- PV: O^T[d][q] += V^T . P^T, B from registers ----
    __builtin_amdgcn_s_setprio(1);
#pragma unroll
    for (int cbp = 0; cbp < 4; cbp++) {
      bf16x4 vf[4];
#pragma unroll
      for (int cb = 0; cb < 4; cb++) {
        const int ch = ((((2 * cb + (quad >> 1)) << 4)) ^ rx) + vhalf;
        vf[cb] = *(const bf16x4*)((const char*)sV + cbp * 2048 + frow + ch);
      }
#pragma unroll
      for (int cb = 0; cb < 4; cb++)
        O[cbp] = __builtin_amdgcn_mfma_f32_16x16x16bf16_1k(vf[cb], p[cb], O[cbp], 0, 0, 0);
    }
    __builtin_amdgcn_s_setprio(0);
  }

  // deferred cross-quad sum reduce (keys split across quads)
  lsum += __shfl_xor(lsum, 16);
  lsum += __shfl_xor(lsum, 32);
  const float inv = 1.f / lsum;
#pragma unroll
  for (int cb = 0; cb < 4; cb++) {
    ushort4 o4;
    o4.x = f2bf(O[cb][0] * inv); o4.y = f2bf(O[cb][1] * inv);
    o4.z = f2bf(O[cb][2] * inv); o4.w = f2bf(O[cb][3] * inv);
    *(ushort4*)&AO[(((size_t)b << 10) + qg) * DIM_ + h * DH_ + 16 * cb + (quad << 2)] = o4;
  }
}

// ---------------- Kernel 3: output projection 128x64, dbuf + XCD remap -----
// Same T1 remap + T4 schedule as qkv.
__global__ __launch_bounds__(256, 3) void proj_gemm(
    const u16* __restrict__ Ab, const u16* __restrict__ Bb,
    const float* __restrict__ Pb, float* __restrict__ Out) {
  __shared__ __align__(16) u16 sA[2][128 * 64];
  __shared__ __align__(16) u16 sB[2][64 * 64];
  const int t = threadIdx.x;
  const int wv = t >> 6, lane = t & 63, quad = (lane >> 4) & 3, l15 = lane & 15;

  const int bid = blockIdx.x;
  const int xcd = bid & 7;
  const int s = bid >> 3;            // 0..63
  const int nti = s >> 3;            // 0..7
  const int m0 = (xcd * 8 + (s & 7)) * 128;
  const int n0 = nti * 64;

  const int srow = lane >> 3;
  const int schunk = (lane & 7) ^ srow;
  const size_t ga = (size_t)(m0 + srow) * DIM_ + schunk * 8;
  const size_t gb = (size_t)(n0 + srow) * DIM_ + schunk * 8;

  f32x4 zero = {0.f, 0.f, 0.f, 0.f};
  f32x4 acc[2][4];
#pragma unroll
  for (int i = 0; i < 2; i++)
#pragma unroll
    for (int j = 0; j < 4; j++) acc[i][j] = zero;

  auto stage = [&](int buf, int k0) {
#pragma unroll
    for (int i = 0; i < 4; i++) {
      const int rb = 32 * wv + 8 * i;
      cp16(Ab + ga + (size_t)rb * DIM_ + k0, &sA[buf][rb * 64]);
    }
#pragma unroll
    for (int i = 0; i < 2; i++) {
      const int rb = 16 * wv + 8 * i;
      cp16(Bb + gb + (size_t)rb * DIM_ + k0, &sB[buf][rb * 64]);
    }
  };

  stage(0, 0);
  for (int kt = 0; kt < 8; kt++) {
    const int cur = kt & 1;
    asm volatile("s_barrier" ::: "memory");
    if (kt < 7) {
      stage(cur ^ 1, (kt + 1) * 64);
      asm volatile("s_waitcnt vmcnt(6)" ::: "memory");
    } else {
      asm volatile("s_waitcnt vmcnt(0)" ::: "memory");
    }
    asm volatile("s_barrier" ::: "memory");
#pragma unroll
    for (int ks = 0; ks < 2; ks++) {
      bf16x8 af[2], bfv[4];
#pragma unroll
      for (int i = 0; i < 2; i++)
        af[i] = *(const bf16x8*)&sA[cur][(wv * 32 + 16 * i + l15) * 64 +
                                        (((ks << 2) | quad) ^ (l15 & 7)) * 8];
#pragma unroll
      for (int j = 0; j < 4; j++)
        bfv[j] = *(const bf16x8*)&sB[cur][(16 * j + l15) * 64 +
                                         (((ks << 2) | quad) ^ (l15 & 7)) * 8];
      __builtin_amdgcn_s_setprio(1);
#pragma unroll
      for (int i = 0; i < 2; i++)
#pragma unroll
        for (int j = 0; j < 4; j++)
          acc[i][j] = __builtin_amdgcn_mfma_f32_16x16x32_bf16(af[i], bfv[j], acc[i][j], 0, 0, 0);
      __builtin_amdgcn_s_setprio(0);
    }
  }

#pragma unroll
  for (int j = 0; j < 4; j++) {
    const int jg = n0 + 16 * j + l15;
    const float pb = Pb[jg];
#pragma unroll
    for (int i = 0; i < 2; i++) {
      const int mbase = m0 + wv * 32 + 16 * i + quad * 4;
#pragma unroll
      for (int rr = 0; rr < 4; rr++)
        Out[(size_t)(mbase + rr) * DIM_ + jg] = acc[i][j][rr] + pb;
    }
  }
}

extern "C" void kernel_launch(void* const* d_in, const int* in_sizes, int n_in,
                              void* d_out, int out_size, void* d_ws, size_t ws_size,
                              hipStream_t stream) {
  const float* x      = (const float*)d_in[0];
  const float* rpe    = (const float*)d_in[1];
  const float* qkv_w  = (const float*)d_in[2];
  const float* proj_w = (const float*)d_in[3];
  const float* proj_b = (const float*)d_in[4];
  float* out = (float*)d_out;

  const size_t perbuf = (size_t)B_ * N_ * DIM_;   // 4,194,304
  u16* Xb  = (u16*)d_ws;          // aliased with AO (lifetimes disjoint)
  u16* Q   = Xb + perbuf;
  u16* K   = Q + perbuf;
  u16* Vt  = K + perbuf;
  u16* Wqb = Vt + perbuf;         // 786,432
  u16* Wpb = Wqb + (size_t)3 * DIM_ * DIM_;  // 262,144
  u16* AO  = Xb;

  convert_kernel<<<2560, 256, 0, stream>>>(x, qkv_w, proj_w, Xb, Wqb, Wpb);
  qkv_gemm<<<1536, 256, 0, stream>>>(Xb, Wqb, Q, K, Vt);
  attn_kernel<<<512, 512, 0, stream>>>(Q, K, Vt, rpe, AO);
  proj_gemm<<<512, 256, 0, stream>>>(AO, Wpb, proj_b, out);
}